// Round 7
// baseline (251.081 us; speedup 1.0000x reference)
//
#include <hip/hip_runtime.h>
#include <stdint.h>

// XOR chain = inclusive prefix-XOR along axis 0 of [S=4096, B=8192] int32.
// Round 21: phase-pipelined single dispatch. Measured phase arithmetic
// (R18/R19/R20): read 128MB ~53us (capped ~2.4 TB/s regardless of in-flight
// bytes => per-CU miss-tracking limit; 5 instruction-level experiments null),
// store 132MB ~20us (fill-rate), lookback ~5-8us; serial sum = the 82-85us
// every variant measures. Fix: hide stores+lookback INSIDE the read window.
// Each block runs 4 chunks of 16 rows (chunk o = i*64+g). After chunk i's
// agg publish, issue chunk i+1's first two DMA stages BEFORE lookback+stores:
// reads never starve (2 stages in flight = 6.7us transfer > 4-6us gap) and
// stores drain under subsequent reads (vmcnt FIFO: stores are older than the
// next consume waits). Only the last chunk's lookback+store is serial tail.
// Predict kernel ~62-67us (53 read-saturated + tail), bench ~215-220.
// Tables: agg/inc 2MB each, poison-self-init (R12-proven valid() scheme).

#define S 4096
#define B4 2048               // v4u column-groups per row
#define TPB 512
#define NCT (B4 / TPB)        // 4 coltiles
#define PH 4                  // chunks (phases) per block
#define CHROWS 16             // rows per chunk
#define NOUT (S / CHROWS)     // 256 chunk-rows
#define NBLK 256              // 1/CU, all resident
#define GRP (NBLK / NCT)      // 64 chunk-rows per phase
#define NWORDS (NOUT * B4)    // 512K dwords = 2 MB per table
#define STG 4                 // rows per stage
#define NSTG (CHROWS / STG)   // 4 stages per chunk

typedef unsigned int v4u __attribute__((ext_vector_type(4)));
typedef unsigned long long u64;
typedef const __attribute__((address_space(1))) v4u* gp1_t;
typedef __attribute__((address_space(3))) v4u* lp3_t;

__device__ __forceinline__ bool valid(unsigned w) {
    return (w & 0x300u) == 0x100u;   // 0xAAAAAAAA poison and 0 both fail
}
__device__ __forceinline__ u64 repl(unsigned nib) {   // nibble -> 16 copies
    u64 m = nib;
    m |= m << 4; m |= m << 8; m |= m << 16; m |= m << 32;
    return m;
}

__global__ __launch_bounds__(TPB) void xor_pipe(
        const v4u* __restrict__ in, v4u* __restrict__ out,
        unsigned* __restrict__ ctl) {
    unsigned* agg = ctl + 64;
    unsigned* inc = agg + NWORDS;

    __shared__ v4u sh[2][STG][TPB];   // 64 KB, per-wave-private slabs

    const int tid   = (int)threadIdx.x;
    const int bid   = (int)blockIdx.x;
    const int ct    = bid & (NCT - 1);
    const int g     = bid >> 2;              // 0..63
    const int colg  = ct * TPB + tid;
    const int wbase = tid & ~63;             // wave-uniform lane base

    // DMA one 4-row stage into buffer buf; grow = global row index.
    auto STAGE = [&](int grow, int buf) {
#pragma unroll
        for (int j = 0; j < STG; ++j)
            __builtin_amdgcn_global_load_lds(
                (gp1_t)(const void*)(in + (size_t)(grow + j) * B4 + colg),
                (lp3_t)(void*)&sh[buf][j][wbase], 16, 0, 0);
    };

    int o = g;                        // phase-0 chunk index
    STAGE(o * CHROWS, 0);             // prologue: stages 0,1 of chunk 0
    STAGE(o * CHROWS + STG, 1);

    for (int i = 0; i < PH; ++i) {
        // ---- Consume 4 stages (R17-proven double-buffer; at s=0 the wait
        // also drains older NT stores from the previous phase -- harmless,
        // they overlap these stages' already-in-flight loads). ----
        u64 q = 0ull;
#pragma unroll
        for (int s = 0; s < NSTG; ++s) {
            if (s < NSTG - 1) asm volatile("s_waitcnt vmcnt(4)" ::: "memory");
            else              asm volatile("s_waitcnt vmcnt(0)" ::: "memory");
            const int buf = s & 1;
#pragma unroll
            for (int j = 0; j < STG; ++j) {
                v4u v = sh[buf][j][tid];
                unsigned n = (v.x & 1u) | ((v.y & 1u) << 1) |
                             ((v.z & 1u) << 2) | ((v.w & 1u) << 3);
                q ^= (u64)n << (4 * (s * STG + j));
            }
            asm volatile("s_waitcnt lgkmcnt(0)" ::: "memory");
            if (s + 2 < NSTG) STAGE(o * CHROWS + (s + 2) * STG, buf);
        }

        // ---- Publish aggregate nibble EARLY (successors poll it) ----
        u64 tt = q;
        tt ^= tt >> 32; tt ^= tt >> 16; tt ^= tt >> 8; tt ^= tt >> 4;
        const unsigned myagg = (unsigned)tt & 0xFu;
        __hip_atomic_store(&agg[(size_t)o * B4 + colg], 0x100u | myagg,
                           __ATOMIC_RELAXED, __HIP_MEMORY_SCOPE_AGENT);

        // ---- Issue next chunk's stages 0,1 NOW: reads stay in flight
        // through the lookback + store gap below. ----
        const int onext = o + GRP;
        if (i + 1 < PH) {
            STAGE(onext * CHROWS, 0);
            STAGE(onext * CHROWS + STG, 1);
        }

        // ---- Lookback: inc fast path + 16-wide batched agg polls ----
        unsigned ex = 0u;
        int k = o - 1;
        while (k >= 0) {
            unsigned iw = __hip_atomic_load(&inc[(size_t)k * B4 + colg],
                                            __ATOMIC_RELAXED,
                                            __HIP_MEMORY_SCOPE_AGENT);
            if (valid(iw)) { ex ^= (iw & 0xFu); break; }
            int n = (k + 1 < 16) ? (k + 1) : 16;
            unsigned a[16];
            for (int j = 0; j < n; ++j)
                a[j] = __hip_atomic_load(&agg[(size_t)(k - j) * B4 + colg],
                                         __ATOMIC_RELAXED,
                                         __HIP_MEMORY_SCOPE_AGENT);
            int consumed = 0;
            for (int j = 0; j < n; ++j) {
                if (valid(a[j])) { ex ^= (a[j] & 0xFu); ++consumed; }
                else break;
            }
            k -= consumed;
            if (consumed == 0) __builtin_amdgcn_s_sleep(1);
        }
        __hip_atomic_store(&inc[(size_t)o * B4 + colg], 0x100u | (ex ^ myagg),
                           __ATOMIC_RELAXED, __HIP_MEMORY_SCOPE_AGENT);

        // ---- Scan (shift-XOR), seed, unpack, NT store (drains under the
        // next phase's read waits). ----
        u64 x = q;
        x ^= x << 4; x ^= x << 8; x ^= x << 16; x ^= x << 32;  // prefix-XOR
        const u64 f = x ^ repl(ex);
        v4u* qo = out + (size_t)o * CHROWS * B4 + colg;
#pragma unroll
        for (int j = 0; j < CHROWS; ++j) {
            const unsigned n = (unsigned)(f >> (4 * j)) & 0xFu;
            v4u ov = (v4u){n & 1u, (n >> 1) & 1u, (n >> 2) & 1u, (n >> 3) & 1u};
            __builtin_nontemporal_store(ov, &qo[(size_t)j * B4]);
        }

        o = onext;
    }
}

extern "C" void kernel_launch(void* const* d_in, const int* in_sizes, int n_in,
                              void* d_out, int out_size, void* d_ws, size_t ws_size,
                              hipStream_t stream) {
    const v4u* in = (const v4u*)d_in[0];
    v4u* out = (v4u*)d_out;
    unsigned* ctl = (unsigned*)d_ws;  // [0..63] ctl, then agg + inc (2 MB each)

    xor_pipe<<<NBLK, TPB, 0, stream>>>(in, out, ctl);
}

// Round 8
// 239.022 us; speedup vs baseline: 1.0505x; 1.0505x over previous
//
#include <hip/hip_runtime.h>
#include <stdint.h>

// XOR chain = inclusive prefix-XOR along axis 0 of [S=4096, B=8192] int32.
// Round 22: contiguous-per-block access. Standing facts: pure reads cap at
// 2.4 TB/s (R19 reduce) across every engine/scope tried, yet m13's float4
// copy does 3.15 TB/s READ concurrently with 3.15 TB/s write. Difference:
// m13 blocks stream contiguous slabs; ours read 64 x 8KB slabs at 32KB
// stride (256 blocks spraying 16K scattered slabs => HBM page thrash;
// HBM-side read rate during our read phase is only 1.26 TB/s per FETCH).
// Fix: block o owns rows [16o,16o+16) = ONE contiguous 512KB slab for both
// read and store. Thread t owns col-groups {t,t+512,t+1024,t+1536}; per row
// its wave's 4 DMAs are each 1KB-contiguous; the block walks its slab
// linearly. Load engine + vmcnt discipline (loads only in the consume loop;
// R21's store-in-vmcnt trap avoided), 16-wide batched lookback, poison-
// self-init tables unchanged. Lookback payload now 16 bits (4 nibbles per
// thread), validity marker at bit16 (0x0001xxxx; poison 0xAAAA____ fails).
// Predict: read 53->38-45us, kernel 83.7->62-72us, bench ~216-226 if the
// pattern theory is right; null => genuine fabric/CU read cap, ceiling case.

#define S 4096
#define B4 2048               // v4u column-groups per row
#define TPB 512
#define CHROWS 16             // rows per chunk = per block
#define NOUT (S / CHROWS)     // 256 chunks
#define NBLK NOUT             // 256 blocks, 1/CU, all resident
#define POISON 0xAAAAAAAAu

typedef unsigned int v4u __attribute__((ext_vector_type(4)));
typedef unsigned long long u64;
typedef const __attribute__((address_space(1))) v4u* gp1_t;
typedef __attribute__((address_space(3))) v4u* lp3_t;

__device__ __forceinline__ bool validw(unsigned w) {
    return (w & 0xFFFF0000u) == 0x00010000u;  // poison/zero both fail
}
__device__ __forceinline__ u64 repl(unsigned nib) {   // nibble -> 16 copies
    u64 m = nib;
    m |= m << 4; m |= m << 8; m |= m << 16; m |= m << 32;
    return m;
}

__global__ __launch_bounds__(TPB) void xor_contig(
        const v4u* __restrict__ in, v4u* __restrict__ out,
        unsigned* __restrict__ ctl) {
    unsigned* agg = ctl + 64;                 // [NOUT][TPB] u32 = 512 KB
    unsigned* inc = agg + (size_t)NOUT * TPB; // 512 KB

    __shared__ v4u lds[2][4][TPB];            // 64 KB, double-buffered rows

    const int tid   = (int)threadIdx.x;
    const int o     = (int)blockIdx.x;        // chunk == block
    const int wbase = tid & ~63;              // wave-uniform lane base

    const v4u* base = in + (size_t)o * CHROWS * B4;   // contiguous 512 KB

    // DMA one full row (4 x 1KB-contiguous per wave) into buffer buf.
    auto STAGE = [&](int row, int buf) {
#pragma unroll
        for (int k = 0; k < 4; ++k)
            __builtin_amdgcn_global_load_lds(
                (gp1_t)(const void*)(base + (size_t)row * B4 + k * TPB + tid),
                (lp3_t)(void*)&lds[buf][k][wbase], 16, 0, 0);
    };

    // ---- Read 16 rows, double-buffered, loads-only vmcnt discipline ----
    u64 q[4] = {0ull, 0ull, 0ull, 0ull};      // one nibble-chain per col-group
    STAGE(0, 0);
    STAGE(1, 1);
#pragma unroll
    for (int s = 0; s < CHROWS; ++s) {
        if (s < CHROWS - 1) asm volatile("s_waitcnt vmcnt(4)" ::: "memory");
        else                asm volatile("s_waitcnt vmcnt(0)" ::: "memory");
        const int buf = s & 1;
#pragma unroll
        for (int k = 0; k < 4; ++k) {
            v4u v = lds[buf][k][tid];
            unsigned n = (v.x & 1u) | ((v.y & 1u) << 1) |
                         ((v.z & 1u) << 2) | ((v.w & 1u) << 3);
            q[k] ^= (u64)n << (4 * s);
        }
        asm volatile("s_waitcnt lgkmcnt(0)" ::: "memory");
        if (s + 2 < CHROWS) STAGE(s + 2, buf);
    }

    // ---- Publish packed 16-bit aggregate (4 nibbles, one per col-group) ----
    unsigned agg16 = 0u;
#pragma unroll
    for (int k = 0; k < 4; ++k) {
        u64 tt = q[k];
        tt ^= tt >> 32; tt ^= tt >> 16; tt ^= tt >> 8; tt ^= tt >> 4;
        agg16 |= ((unsigned)tt & 0xFu) << (4 * k);
    }
    __hip_atomic_store(&agg[(size_t)o * TPB + tid], 0x00010000u | agg16,
                       __ATOMIC_RELAXED, __HIP_MEMORY_SCOPE_AGENT);

    // ---- Lookback: inc fast path + 16-wide batched agg polls ----
    unsigned ex16 = 0u;
    int k = o - 1;
    while (k >= 0) {
        unsigned iw = __hip_atomic_load(&inc[(size_t)k * TPB + tid],
                                        __ATOMIC_RELAXED,
                                        __HIP_MEMORY_SCOPE_AGENT);
        if (validw(iw)) { ex16 ^= (iw & 0xFFFFu); break; }
        int n = (k + 1 < 16) ? (k + 1) : 16;
        unsigned a[16];
        for (int j = 0; j < n; ++j)
            a[j] = __hip_atomic_load(&agg[(size_t)(k - j) * TPB + tid],
                                     __ATOMIC_RELAXED,
                                     __HIP_MEMORY_SCOPE_AGENT);
        int consumed = 0;
        for (int j = 0; j < n; ++j) {
            if (validw(a[j])) { ex16 ^= (a[j] & 0xFFFFu); ++consumed; }
            else break;
        }
        k -= consumed;
        if (consumed == 0) __builtin_amdgcn_s_sleep(1);
    }
    __hip_atomic_store(&inc[(size_t)o * TPB + tid],
                       0x00010000u | (ex16 ^ agg16),
                       __ATOMIC_RELAXED, __HIP_MEMORY_SCOPE_AGENT);

    // ---- Scan each col-group chain, seed, unpack, NT store (contiguous) ----
    u64 f[4];
#pragma unroll
    for (int kk = 0; kk < 4; ++kk) {
        u64 x = q[kk];
        x ^= x << 4; x ^= x << 8; x ^= x << 16; x ^= x << 32;  // prefix-XOR
        f[kk] = x ^ repl((ex16 >> (4 * kk)) & 0xFu);
    }
    v4u* ob = out + (size_t)o * CHROWS * B4;
#pragma unroll
    for (int j = 0; j < CHROWS; ++j) {
#pragma unroll
        for (int kk = 0; kk < 4; ++kk) {
            const unsigned n = (unsigned)(f[kk] >> (4 * j)) & 0xFu;
            v4u ov = (v4u){n & 1u, (n >> 1) & 1u, (n >> 2) & 1u, (n >> 3) & 1u};
            __builtin_nontemporal_store(ov, &ob[(size_t)j * B4 + kk * TPB + tid]);
        }
    }
}

extern "C" void kernel_launch(void* const* d_in, const int* in_sizes, int n_in,
                              void* d_out, int out_size, void* d_ws, size_t ws_size,
                              hipStream_t stream) {
    const v4u* in = (const v4u*)d_in[0];
    v4u* out = (v4u*)d_out;
    unsigned* ctl = (unsigned*)d_ws;  // [0..63] ctl, then agg + inc (512 KB each)

    xor_contig<<<NBLK, TPB, 0, stream>>>(in, out, ctl);
}